// Round 13
// baseline (788.292 us; speedup 1.0000x reference)
//
#include <hip/hip_runtime.h>
#include <hip/hip_bf16.h>
#include <hip/hip_fp16.h>

#define N_NODES 100000
#define N_EDGES 3200000
#define NFEAT 512
#define HDIM 64
#define NCLASS 40
#define N_LAYERS 4
#define NEG_SLOPE 0.2f

#define NSLICE 8
#define SL_W 12500                  // nodes per slice
#define CAP 440000                  // per-slice segment capacity
#define BATCH 4096                  // edges per partition block
#define PBLOCKS ((N_EDGES + BATCH - 1) / BATCH)   // 782
#define SCUR_PAD 16                 // counters on separate 64B lines

#define NBIN 49                     // buckets per slice (256 nodes each)
#define NBUCKET (NSLICE * NBIN)     // 392
#define CAP2 9216                   // per-bucket capacity
#define BPS ((CAP + BATCH - 1) / BATCH)   // pass-B blocks per slice
#define NCOUNT ((NSLICE + NBUCKET) * SCUR_PAD)   // ints to zero

#define AGG_BLOCKS 2048             // persistent-wave grid for aggregation

typedef __attribute__((ext_vector_type(8))) _Float16 half8;
typedef __attribute__((ext_vector_type(4))) float floatx4;

__device__ __forceinline__ float leaky(float x) {
    return x >= 0.f ? x : NEG_SLOPE * x;
}

__global__ void zero_counters_kernel(int* __restrict__ p) {
    int i = blockIdx.x * blockDim.x + threadIdx.x;
    if (i < NCOUNT) p[i] = 0;
}

// ---------------- CSR build (deterministic 2-level bucket sort) ----------------

__global__ __launch_bounds__(256) void partition_seg_kernel(const int* __restrict__ ei,
                                                            int* __restrict__ scur,
                                                            unsigned* __restrict__ pairs) {
    __shared__ unsigned buf[BATCH];
    __shared__ int cnt[NSLICE];
    __shared__ int off[NSLICE + 1];
    __shared__ int gbase[NSLICE];
    int t = threadIdx.x;
    int lane = t & 63;
    long long base = (long long)blockIdx.x * BATCH;

    unsigned key[16];
    int bin[16];
#pragma unroll
    for (int i = 0; i < 16; ++i) {
        long long e = base + i * 256 + t;
        if (e < N_EDGES) {
            int s = ei[e];
            int d = ei[N_EDGES + e];
            int b = d / SL_W;
            bin[i] = b;
            key[i] = (unsigned)s | ((unsigned)(d - b * SL_W) << 17);
        } else {
            bin[i] = -1;
            key[i] = 0;
        }
    }
    if (t < NSLICE) cnt[t] = 0;
    __syncthreads();

#pragma unroll
    for (int i = 0; i < 16; ++i) {
        int b = bin[i];
#pragma unroll
        for (int s = 0; s < NSLICE; ++s) {
            unsigned long long mask = __ballot(b == s);
            if (mask && lane == (__ffsll((long long)mask) - 1))
                atomicAdd(&cnt[s], __popcll(mask));
        }
    }
    __syncthreads();
    if (t == 0) {
        int run = 0;
#pragma unroll
        for (int s = 0; s < NSLICE; ++s) { off[s] = run; run += cnt[s]; }
        off[NSLICE] = run;
    }
    __syncthreads();
    if (t < NSLICE) {
        gbase[t] = atomicAdd(&scur[t * SCUR_PAD], cnt[t]);
        cnt[t] = 0;
    }
    __syncthreads();

#pragma unroll
    for (int i = 0; i < 16; ++i) {
        int b = bin[i];
#pragma unroll
        for (int s = 0; s < NSLICE; ++s) {
            unsigned long long mask = __ballot(b == s);
            if (!mask) continue;
            int leader = __ffsll((long long)mask) - 1;
            int bp = 0;
            if (lane == leader) bp = atomicAdd(&cnt[s], __popcll(mask));
            bp = __shfl(bp, leader);
            if (b == s) {
                int rank = __popcll(mask & ((1ull << lane) - 1));
                buf[off[s] + bp + rank] = key[i];
            }
        }
    }
    __syncthreads();

    int total = off[NSLICE];
    for (int p = t; p < total; p += 256) {
        int b = NSLICE - 1;
#pragma unroll
        for (int q = NSLICE - 2; q >= 0; --q)
            if (p < off[q + 1]) b = q;
        int idx = gbase[b] + (p - off[b]);
        if (idx < CAP) pairs[(size_t)b * CAP + idx] = buf[p];
    }
}

__global__ __launch_bounds__(256) void partition2_kernel(const int* __restrict__ scur,
                                                         const unsigned* __restrict__ pairs,
                                                         int* __restrict__ scur2,
                                                         unsigned* __restrict__ pairs2) {
    __shared__ unsigned buf[BATCH];
    __shared__ int cnt[NBIN];
    __shared__ int off[NBIN + 1];
    __shared__ int gb[NBIN];
    int slice = blockIdx.x / BPS;
    int batch = blockIdx.x % BPS;
    int cnt_s = scur[slice * SCUR_PAD];
    if (cnt_s > CAP) cnt_s = CAP;
    int base = batch * BATCH;
    if (base >= cnt_s) return;
    int n = cnt_s - base; if (n > BATCH) n = BATCH;
    const unsigned* seg = pairs + (size_t)slice * CAP + base;
    int t = threadIdx.x;
    if (t < NBIN) cnt[t] = 0;
    __syncthreads();

    unsigned key[16];
    int bn[16];
#pragma unroll
    for (int i = 0; i < 16; ++i) {
        int idx = i * 256 + t;
        if (idx < n) {
            unsigned k = seg[idx];
            key[i] = k;
            int b = (int)(k >> 17) >> 8;
            bn[i] = b;
            atomicAdd(&cnt[b], 1);
        } else {
            bn[i] = -1;
        }
    }
    __syncthreads();
    if (t == 0) {
        int run = 0;
        for (int s = 0; s < NBIN; ++s) { off[s] = run; run += cnt[s]; }
        off[NBIN] = run;
    }
    __syncthreads();
    if (t < NBIN) {
        gb[t] = atomicAdd(&scur2[(slice * NBIN + t) * SCUR_PAD], cnt[t]);
        cnt[t] = 0;
    }
    __syncthreads();
#pragma unroll
    for (int i = 0; i < 16; ++i) {
        if (bn[i] >= 0) {
            int p = atomicAdd(&cnt[bn[i]], 1);
            buf[off[bn[i]] + p] = key[i];
        }
    }
    __syncthreads();
    int total = off[NBIN];
    for (int p = t; p < total; p += 256) {
        int lo = 0, hi = NBIN - 1;
        while (lo < hi) {
            int mid = (lo + hi + 1) >> 1;
            if (off[mid] <= p) lo = mid; else hi = mid - 1;
        }
        int idx = gb[lo] + (p - off[lo]);
        if (idx < CAP2) pairs2[(size_t)(slice * NBIN + lo) * CAP2 + idx] = buf[p];
    }
}

__global__ __launch_bounds__(512) void scan_buckets_kernel(const int* __restrict__ scur2,
                                                           int* __restrict__ bbase) {
    __shared__ int s[512];
    int t = threadIdx.x;
    int v = 0;
    if (t < NBUCKET) {
        v = scur2[t * SCUR_PAD];
        if (v > CAP2) v = CAP2;
    }
    s[t] = v;
    __syncthreads();
    for (int off = 1; off < 512; off <<= 1) {
        int x = (t >= off) ? s[t - off] : 0;
        __syncthreads();
        s[t] += x;
        __syncthreads();
    }
    if (t < NBUCKET) bbase[t] = s[t] - v;
    if (t == NBUCKET - 1) bbase[NBUCKET] = s[t];
}

__global__ __launch_bounds__(256) void bucket_sort_kernel(const int* __restrict__ scur2,
                                                          const int* __restrict__ bbase,
                                                          const unsigned* __restrict__ pairs2,
                                                          int* __restrict__ col,
                                                          int* __restrict__ rp) {
    __shared__ int hist[256];
    __shared__ int cur[256];
    __shared__ unsigned outb[CAP2];
    int b = blockIdx.x;
    int slice = b / NBIN, bin = b % NBIN;
    int c = scur2[b * SCUR_PAD]; if (c > CAP2) c = CAP2;
    const unsigned* seg = pairs2 + (size_t)b * CAP2;
    int t = threadIdx.x;
    int nlo = slice * SL_W + bin * 256;
    int nnodes = SL_W - bin * 256; if (nnodes > 256) nnodes = 256;
    hist[t] = 0;
    __syncthreads();
    for (int i = t; i < c; i += 256) atomicAdd(&hist[(seg[i] >> 17) & 255], 1);
    __syncthreads();
    int v = hist[t];
    for (int off = 1; off < 256; off <<= 1) {
        int x = (t >= off) ? hist[t - off] : 0;
        __syncthreads();
        hist[t] += x;
        __syncthreads();
    }
    int excl = hist[t] - v;
    cur[t] = excl;
    int base = bbase[b];
    if (t < nnodes) rp[nlo + t] = base + excl;
    if (b == NBUCKET - 1 && t == 0) rp[N_NODES] = base + c;
    __syncthreads();
    for (int i = t; i < c; i += 256) {
        unsigned k = seg[i];
        int p = atomicAdd(&cur[(k >> 17) & 255], 1);
        outb[p] = k & 0x1FFFFu;
    }
    __syncthreads();
    for (int i = t; i < c; i += 256) col[base + i] = (int)outb[i];
}

// ---------------- MFMA input GEMM: C[M x 64] = A[M x 512] @ B[512 x 64] + bias ----------------

__global__ __launch_bounds__(256) void gemm_in_mfma(const float* __restrict__ A,
                                                    const float* __restrict__ B,
                                                    const float* __restrict__ bias,
                                                    float* __restrict__ C, int M) {
    __shared__ _Float16 As[2][64][40];
    __shared__ _Float16 Bt[2][64][40];
    int t = threadIdx.x;
    int lane = t & 63;
    int wid = t >> 6;
    int row0 = blockIdx.x * 64;

    floatx4 acc[4];
#pragma unroll
    for (int ct = 0; ct < 4; ++ct) acc[ct] = (floatx4){0.f, 0.f, 0.f, 0.f};

#define STAGE_A(buf, kt)                                                           \
    {                                                                              \
        int r = t >> 2, kq = (t & 3) << 3;                                         \
        int gr = row0 + r;                                                         \
        float4 v0 = make_float4(0.f, 0.f, 0.f, 0.f), v1 = v0;                      \
        if (gr < M) {                                                              \
            v0 = *(const float4*)&A[(size_t)gr * 512 + (kt) * 32 + kq];            \
            v1 = *(const float4*)&A[(size_t)gr * 512 + (kt) * 32 + kq + 4];        \
        }                                                                          \
        half8 h;                                                                   \
        h[0] = (_Float16)v0.x; h[1] = (_Float16)v0.y;                              \
        h[2] = (_Float16)v0.z; h[3] = (_Float16)v0.w;                              \
        h[4] = (_Float16)v1.x; h[5] = (_Float16)v1.y;                              \
        h[6] = (_Float16)v1.z; h[7] = (_Float16)v1.w;                              \
        *(half8*)&As[buf][r][kq] = h;                                              \
    }

#define STAGE_B(buf, kt)                                                           \
    {                                                                              \
        int k = t >> 3, n0 = (t & 7) << 3;                                         \
        float4 w0 = *(const float4*)&B[(size_t)((kt) * 32 + k) * 64 + n0];         \
        float4 w1 = *(const float4*)&B[(size_t)((kt) * 32 + k) * 64 + n0 + 4];     \
        Bt[buf][n0 + 0][k] = (_Float16)w0.x; Bt[buf][n0 + 1][k] = (_Float16)w0.y;  \
        Bt[buf][n0 + 2][k] = (_Float16)w0.z; Bt[buf][n0 + 3][k] = (_Float16)w0.w;  \
        Bt[buf][n0 + 4][k] = (_Float16)w1.x; Bt[buf][n0 + 5][k] = (_Float16)w1.y;  \
        Bt[buf][n0 + 6][k] = (_Float16)w1.z; Bt[buf][n0 + 7][k] = (_Float16)w1.w;  \
    }

    STAGE_A(0, 0)
    STAGE_B(0, 0)
    __syncthreads();
    for (int kt = 0; kt < 16; ++kt) {
        int buf = kt & 1;
        if (kt < 15) {
            STAGE_A(buf ^ 1, kt + 1)
            STAGE_B(buf ^ 1, kt + 1)
        }
        half8 a = *(half8*)&As[buf][wid * 16 + (lane & 15)][(lane >> 4) * 8];
#pragma unroll
        for (int ct = 0; ct < 4; ++ct) {
            half8 b = *(half8*)&Bt[buf][ct * 16 + (lane & 15)][(lane >> 4) * 8];
            acc[ct] = __builtin_amdgcn_mfma_f32_16x16x32_f16(a, b, acc[ct], 0, 0, 0);
        }
        __syncthreads();
    }
#pragma unroll
    for (int ct = 0; ct < 4; ++ct) {
        int colg = ct * 16 + (lane & 15);
        float bv = bias[colg];
#pragma unroll
        for (int i = 0; i < 4; ++i) {
            int gr = row0 + wid * 16 + (lane >> 4) * 4 + i;
            if (gr < M) C[(size_t)gr * 64 + colg] = acc[ct][i] + bv;
        }
    }
#undef STAGE_A
#undef STAGE_B
}

// ---------------- MFMA fused layer GEMM: h2 = A @ W  + att dots + fp16 store ----------------

__global__ __launch_bounds__(256) void gemm_fused_mfma(const float* __restrict__ A,
                                                       const float* __restrict__ W,
                                                       const float* __restrict__ att_s_g,
                                                       const float* __restrict__ att_d_g,
                                                       float* __restrict__ as_,
                                                       float* __restrict__ ad_,
                                                       __half* __restrict__ h2h, int M) {
    __shared__ _Float16 As[64][72];
    __shared__ _Float16 Wt[64][72];
    __shared__ float sATT[128];
    int t = threadIdx.x;
    int lane = t & 63;
    int wid = t >> 6;
    int row0 = blockIdx.x * 64;
    if (t < 128) sATT[t] = (t < 64) ? att_s_g[t] : att_d_g[t - 64];

    {
        int r = t >> 2, kq = (t & 3) << 4;
        int gr = row0 + r;
        float4 v0 = make_float4(0.f, 0.f, 0.f, 0.f), v1 = v0, v2 = v0, v3 = v0;
        if (gr < M) {
            const float* ap = &A[(size_t)gr * 64 + kq];
            v0 = *(const float4*)(ap + 0);
            v1 = *(const float4*)(ap + 4);
            v2 = *(const float4*)(ap + 8);
            v3 = *(const float4*)(ap + 12);
        }
        half8 h0, h1;
        h0[0] = (_Float16)v0.x; h0[1] = (_Float16)v0.y; h0[2] = (_Float16)v0.z; h0[3] = (_Float16)v0.w;
        h0[4] = (_Float16)v1.x; h0[5] = (_Float16)v1.y; h0[6] = (_Float16)v1.z; h0[7] = (_Float16)v1.w;
        h1[0] = (_Float16)v2.x; h1[1] = (_Float16)v2.y; h1[2] = (_Float16)v2.z; h1[3] = (_Float16)v2.w;
        h1[4] = (_Float16)v3.x; h1[5] = (_Float16)v3.y; h1[6] = (_Float16)v3.z; h1[7] = (_Float16)v3.w;
        *(half8*)&As[r][kq] = h0;
        *(half8*)&As[r][kq + 8] = h1;
    }
    {
        int k = t >> 2, n0 = (t & 3) << 4;
        const float* wp = &W[(size_t)k * 64 + n0];
        float4 w0 = *(const float4*)(wp + 0);
        float4 w1 = *(const float4*)(wp + 4);
        float4 w2 = *(const float4*)(wp + 8);
        float4 w3 = *(const float4*)(wp + 12);
        float wv[16] = {w0.x, w0.y, w0.z, w0.w, w1.x, w1.y, w1.z, w1.w,
                        w2.x, w2.y, w2.z, w2.w, w3.x, w3.y, w3.z, w3.w};
#pragma unroll
        for (int j = 0; j < 16; ++j) Wt[n0 + j][k] = (_Float16)wv[j];
    }
    __syncthreads();

    floatx4 acc[4];
#pragma unroll
    for (int ct = 0; ct < 4; ++ct) acc[ct] = (floatx4){0.f, 0.f, 0.f, 0.f};
#pragma unroll
    for (int kt = 0; kt < 2; ++kt) {
        half8 a = *(half8*)&As[wid * 16 + (lane & 15)][kt * 32 + (lane >> 4) * 8];
#pragma unroll
        for (int ct = 0; ct < 4; ++ct) {
            half8 b = *(half8*)&Wt[ct * 16 + (lane & 15)][kt * 32 + (lane >> 4) * 8];
            acc[ct] = __builtin_amdgcn_mfma_f32_16x16x32_f16(a, b, acc[ct], 0, 0, 0);
        }
    }

    int c15 = lane & 15;
    float ps[4] = {0.f, 0.f, 0.f, 0.f}, pd[4] = {0.f, 0.f, 0.f, 0.f};
#pragma unroll
    for (int ct = 0; ct < 4; ++ct) {
        float sa = sATT[ct * 16 + c15];
        float sd = sATT[64 + ct * 16 + c15];
#pragma unroll
        for (int i = 0; i < 4; ++i) {
            ps[i] += acc[ct][i] * sa;
            pd[i] += acc[ct][i] * sd;
        }
    }
#pragma unroll
    for (int off = 1; off < 16; off <<= 1) {
#pragma unroll
        for (int i = 0; i < 4; ++i) {
            ps[i] += __shfl_xor(ps[i], off);
            pd[i] += __shfl_xor(pd[i], off);
        }
    }
    if (c15 == 0) {
#pragma unroll
        for (int i = 0; i < 4; ++i) {
            int gr = row0 + wid * 16 + (lane >> 4) * 4 + i;
            if (gr < M) { as_[gr] = ps[i]; ad_[gr] = pd[i]; }
        }
    }
#pragma unroll
    for (int ct = 0; ct < 4; ++ct) {
        int colg = ct * 16 + c15;
#pragma unroll
        for (int i = 0; i < 4; ++i) {
            int gr = row0 + wid * 16 + (lane >> 4) * 4 + i;
            if (gr < M) h2h[(size_t)gr * 64 + colg] = __float2half(acc[ct][i]);
        }
    }
}

// ---------------- GAT aggregation: pair-split gather (2 edges / mem instr) ----------------
// Lanes 0-31 gather even edges' h-rows as __half2 (32 x 4B = full 128B row);
// lanes 32-63 gather odd edges. Each lane accumulates float2 (features 2f,2f+1)
// for its stream; one shfl_xor(32) merges. Fixed ref point m = e_self.
// Persistent waves: contiguous node ranges amortize launch + col locality.

__global__ __launch_bounds__(256) void gat_aggregate(const int* __restrict__ rp,
                                                     const int* __restrict__ col,
                                                     const __half* __restrict__ h2h,
                                                     const float* __restrict__ as_,
                                                     const float* __restrict__ ad_,
                                                     const float* __restrict__ bias,
                                                     float* __restrict__ h /* in/out */) {
    __shared__ int ss[4][64];
    __shared__ float ww[4][64];
    const __half2* H2 = (const __half2*)h2h;
    int wv = threadIdx.x >> 6;
    int lane = threadIdx.x & 63;
    int half = lane >> 5;      // edge-stream (0 = even edges, 1 = odd)
    int fl = lane & 31;        // feature-pair index (features 2fl, 2fl+1)

    int gw = blockIdx.x * 4 + wv;
    int nwaves = AGG_BLOCKS * 4;
    int per = (N_NODES + nwaves - 1) / nwaves;
    int n0 = gw * per;
    int n1 = n0 + per; if (n1 > N_NODES) n1 = N_NODES;

    for (int wid = n0; wid < n1; ++wid) {
        int beg = rp[wid];
        int end = rp[wid + 1];
        float adv = ad_[wid];
        float m = leaky(as_[wid] + adv);   // fixed reference point

        float2 acc = make_float2(0.f, 0.f);
        if (half == 0) {                   // self term (w = exp(0) = 1), once
            __half2 sv = H2[(size_t)wid * 32 + fl];
            acc.x = __low2float(sv);
            acc.y = __high2float(sv);
        }
        float wsum = 0.f;

        for (int j0 = beg; j0 < end; j0 += 64) {
            int rem = end - j0;
            int cnt = rem < 64 ? rem : 64;
            if (lane < cnt) {
                int s = col[j0 + lane];
                float w = __expf(leaky(as_[s] + adv) - m);
                wsum += w;
                ss[wv][lane] = s;
                ww[wv][lane] = w;
            }
            int j = 0;
            for (; j + 16 <= cnt; j += 16) {   // 8 instrs cover 16 edges
                int sq[8];
#pragma unroll
                for (int q = 0; q < 8; ++q) sq[q] = ss[wv][j + 2 * q + half];
                __half2 hv[8];
#pragma unroll
                for (int q = 0; q < 8; ++q) hv[q] = H2[(size_t)sq[q] * 32 + fl];
#pragma unroll
                for (int q = 0; q < 8; ++q) {
                    float wq = ww[wv][j + 2 * q + half];
                    acc.x = fmaf(wq, __low2float(hv[q]), acc.x);
                    acc.y = fmaf(wq, __high2float(hv[q]), acc.y);
                }
            }
            for (; j < cnt; j += 2) {          // tail, pairwise
                int idx2 = j + half;
                if (idx2 < cnt) {
                    int s = ss[wv][idx2];
                    float wq = ww[wv][idx2];
                    __half2 hvv = H2[(size_t)s * 32 + fl];
                    acc.x = fmaf(wq, __low2float(hvv), acc.x);
                    acc.y = fmaf(wq, __high2float(hvv), acc.y);
                }
            }
        }
        // merge the two edge streams + reduce wsum
        acc.x += __shfl_xor(acc.x, 32);
        acc.y += __shfl_xor(acc.y, 32);
#pragma unroll
        for (int off = 32; off; off >>= 1) wsum += __shfl_xor(wsum, off);
        float denom = wsum + 1.0f;             // self weight exp(0)

        if (half == 0) {                        // coalesced float2 epilogue
            float o0 = acc.x / denom + bias[2 * fl];
            float o1 = acc.y / denom + bias[2 * fl + 1];
            o0 = (o0 > 0.f) ? o0 : expm1f(o0);
            o1 = (o1 > 0.f) ? o1 : expm1f(o1);
            float2* hp = (float2*)&h[(size_t)wid * 64 + 2 * fl];
            float2 hr = *hp;
            *hp = make_float2(hr.x + o0, hr.y + o1);
        }
    }
}

// ---------------- output GEMM: out[N x 40] = h[N x 64] @ W[64 x 40] + b ----------------

__global__ __launch_bounds__(256) void out_gemm(const float* __restrict__ h,
                                                const float* __restrict__ W,
                                                const float* __restrict__ b,
                                                float* __restrict__ out) {
    __shared__ float Ws[64 * 40];
    __shared__ float bs[40];
    int t = threadIdx.x;
    for (int idx = t; idx < 64 * 40; idx += 256) Ws[idx] = W[idx];
    if (t < 40) bs[t] = b[t];
    __syncthreads();
    int wid = blockIdx.x * (blockDim.x >> 6) + (t >> 6);
    int lane = t & 63;
    if (wid >= N_NODES) return;
    float hv = h[(size_t)wid * 64 + lane];
    float acc = (lane < 40) ? bs[lane] : 0.f;
#pragma unroll
    for (int k = 0; k < 64; ++k) {
        float hk = __shfl(hv, k);
        float wv = (lane < 40) ? Ws[k * 40 + lane] : 0.f;
        acc += hk * wv;
    }
    if (lane < 40) out[(size_t)wid * 40 + lane] = acc;
}

// ---------------- launcher ----------------

extern "C" void kernel_launch(void* const* d_in, const int* in_sizes, int n_in,
                              void* d_out, int out_size, void* d_ws, size_t ws_size,
                              hipStream_t stream) {
    const float* x        = (const float*)d_in[0];
    const int* ei         = (const int*)d_in[1];
    const float* W_in     = (const float*)d_in[2];
    const float* b_in     = (const float*)d_in[3];
    const float* W_conv   = (const float*)d_in[4];
    const float* att_src  = (const float*)d_in[5];
    const float* att_dst  = (const float*)d_in[6];
    const float* b_conv   = (const float*)d_in[7];
    const float* W_out    = (const float*)d_in[8];
    const float* b_out    = (const float*)d_in[9];
    float* out = (float*)d_out;

    char* w = (char*)d_ws;
    float*    hA    = (float*)w;    w += (size_t)N_NODES * 64 * 4;
    __half*   h2h   = (__half*)w;   w += (size_t)N_NODES * 64 * 2;
    float*    as_   = (float*)w;    w += (size_t)N_NODES * 4;
    float*    ad_   = (float*)w;    w += (size_t)N_NODES * 4;
    int*      rp    = (int*)w;      w += 400016;
    int*      scur  = (int*)w;      w += NSLICE * SCUR_PAD * 4;
    int*      scur2 = (int*)w;      w += NBUCKET * SCUR_PAD * 4;
    int*      bbase = (int*)w;      w += 4096;
    int*      col   = (int*)w;      w += (size_t)N_EDGES * 4;
    unsigned* pairs = (unsigned*)w; w += (size_t)NSLICE * CAP * 4;
    unsigned* pairs2= (unsigned*)w; w += (size_t)NBUCKET * CAP2 * 4;

    // CSR build
    zero_counters_kernel<<<(NCOUNT + 255) / 256, 256, 0, stream>>>(scur);
    partition_seg_kernel<<<PBLOCKS, 256, 0, stream>>>(ei, scur, pairs);
    partition2_kernel<<<NSLICE * BPS, 256, 0, stream>>>(scur, pairs, scur2, pairs2);
    scan_buckets_kernel<<<1, 512, 0, stream>>>(scur2, bbase);
    bucket_sort_kernel<<<NBUCKET, 256, 0, stream>>>(scur2, bbase, pairs2, col, rp);

    // input transform (MFMA)
    gemm_in_mfma<<<(N_NODES + 63) / 64, 256, 0, stream>>>(x, W_in, b_in, hA, N_NODES);

    for (int l = 0; l < N_LAYERS; ++l) {
        gemm_fused_mfma<<<(N_NODES + 63) / 64, 256, 0, stream>>>(hA, W_conv + (size_t)l * 64 * 64,
                                                                 att_src + l * 64, att_dst + l * 64,
                                                                 as_, ad_, h2h, N_NODES);
        gat_aggregate<<<AGG_BLOCKS, 256, 0, stream>>>(rp, col, h2h, as_, ad_,
                                                      b_conv + l * 64, hA);
    }

    out_gemm<<<N_NODES / 4, 256, 0, stream>>>(hA, W_out, b_out, out);
}

// Round 14
// 611.875 us; speedup vs baseline: 1.2883x; 1.2883x over previous
//
#include <hip/hip_runtime.h>
#include <hip/hip_bf16.h>
#include <hip/hip_fp16.h>

#define N_NODES 100000
#define N_EDGES 3200000
#define NFEAT 512
#define HDIM 64
#define NCLASS 40
#define N_LAYERS 4
#define NEG_SLOPE 0.2f

#define BATCH 4096                  // edges per partition block
#define PBLOCKS ((N_EDGES + BATCH - 1) / BATCH)   // 782
#define SCUR_PAD 16                 // counters on separate 64B lines

#define NB2 ((N_NODES + 255) / 256) // 391 buckets of 256 nodes
#define CAP2 9216                   // per-bucket capacity (mean 8184, +11 sigma)
#define NCOUNT (NB2 * SCUR_PAD)     // ints to zero

typedef __attribute__((ext_vector_type(8))) _Float16 half8;
typedef __attribute__((ext_vector_type(4))) float floatx4;

__device__ __forceinline__ float leaky(float x) {
    return x >= 0.f ? x : NEG_SLOPE * x;
}

__global__ void zero_counters_kernel(int* __restrict__ p) {
    int i = blockIdx.x * blockDim.x + threadIdx.x;
    if (i < NCOUNT) p[i] = 0;
}

// ---------------- CSR build: single-level 391-bucket partition ----------------
// Each block bins one 4096-edge batch into the FINAL 256-node buckets in LDS
// (per-edge LDS atomics over 391 counters), reserves segment space with one
// padded global atomic per nonempty bucket, burst-writes each bucket's run.
// Key = src | (d & 255) << 17.

__global__ __launch_bounds__(256) void partition_direct_kernel(const int* __restrict__ ei,
                                                               int* __restrict__ scur2,
                                                               unsigned* __restrict__ pairs2) {
    __shared__ unsigned buf[BATCH];       // 16 KB reorder buffer
    __shared__ int cnt[NB2];
    __shared__ int off[NB2 + 1];
    __shared__ int gb[NB2];
    int t = threadIdx.x;
    long long base = (long long)blockIdx.x * BATCH;

    unsigned key[16];
    int bn[16];
    for (int i = t; i < NB2; i += 256) cnt[i] = 0;
    __syncthreads();

#pragma unroll
    for (int i = 0; i < 16; ++i) {
        long long e = base + i * 256 + t;
        if (e < N_EDGES) {
            int s = ei[e];
            int d = ei[N_EDGES + e];
            int b = d >> 8;
            bn[i] = b;
            key[i] = (unsigned)s | ((unsigned)(d & 255) << 17);
            atomicAdd(&cnt[b], 1);
        } else {
            bn[i] = -1;
        }
    }
    __syncthreads();
    if (t == 0) {
        int run = 0;
        for (int s2 = 0; s2 < NB2; ++s2) { off[s2] = run; run += cnt[s2]; }
        off[NB2] = run;
    }
    __syncthreads();
    for (int i = t; i < NB2; i += 256) {
        int c = cnt[i];
        gb[i] = c ? atomicAdd(&scur2[i * SCUR_PAD], c) : 0;
        cnt[i] = 0;
    }
    __syncthreads();
#pragma unroll
    for (int i = 0; i < 16; ++i) {
        if (bn[i] >= 0) {
            int p = atomicAdd(&cnt[bn[i]], 1);
            buf[off[bn[i]] + p] = key[i];
        }
    }
    __syncthreads();
    int total = off[NB2];
    for (int p = t; p < total; p += 256) {
        int lo = 0, hi = NB2 - 1;              // largest b with off[b] <= p
        while (lo < hi) {
            int mid = (lo + hi + 1) >> 1;
            if (off[mid] <= p) lo = mid; else hi = mid - 1;
        }
        int idx = gb[lo] + (p - off[lo]);
        if (idx < CAP2) pairs2[(size_t)lo * CAP2 + idx] = buf[p];
    }
}

// Exclusive scan over bucket counts -> bucket base offsets in col.
__global__ __launch_bounds__(512) void scan_buckets_kernel(const int* __restrict__ scur2,
                                                           int* __restrict__ bbase) {
    __shared__ int s[512];
    int t = threadIdx.x;
    int v = 0;
    if (t < NB2) {
        v = scur2[t * SCUR_PAD];
        if (v > CAP2) v = CAP2;
    }
    s[t] = v;
    __syncthreads();
    for (int off = 1; off < 512; off <<= 1) {
        int x = (t >= off) ? s[t - off] : 0;
        __syncthreads();
        s[t] += x;
        __syncthreads();
    }
    if (t < NB2) bbase[t] = s[t] - v;
    if (t == NB2 - 1) bbase[NB2] = s[t];
}

// One block per bucket: LDS node-histogram -> scan (emits rp) -> LDS placement
// -> sequential coalesced col write. No global atomics.
__global__ __launch_bounds__(256) void bucket_sort_kernel(const int* __restrict__ scur2,
                                                          const int* __restrict__ bbase,
                                                          const unsigned* __restrict__ pairs2,
                                                          int* __restrict__ col,
                                                          int* __restrict__ rp) {
    __shared__ int hist[256];
    __shared__ int cur[256];
    __shared__ unsigned outb[CAP2];
    int b = blockIdx.x;
    int c = scur2[b * SCUR_PAD]; if (c > CAP2) c = CAP2;
    const unsigned* seg = pairs2 + (size_t)b * CAP2;
    int t = threadIdx.x;
    int nlo = b * 256;
    int nnodes = N_NODES - nlo; if (nnodes > 256) nnodes = 256;
    hist[t] = 0;
    __syncthreads();
    for (int i = t; i < c; i += 256) atomicAdd(&hist[(seg[i] >> 17) & 255], 1);
    __syncthreads();
    int v = hist[t];
    for (int off = 1; off < 256; off <<= 1) {
        int x = (t >= off) ? hist[t - off] : 0;
        __syncthreads();
        hist[t] += x;
        __syncthreads();
    }
    int excl = hist[t] - v;
    cur[t] = excl;
    int base = bbase[b];
    if (t < nnodes) rp[nlo + t] = base + excl;
    if (b == NB2 - 1 && t == 0) rp[N_NODES] = base + c;
    __syncthreads();
    for (int i = t; i < c; i += 256) {
        unsigned k = seg[i];
        int p = atomicAdd(&cur[(k >> 17) & 255], 1);
        outb[p] = k & 0x1FFFFu;
    }
    __syncthreads();
    for (int i = t; i < c; i += 256) col[base + i] = (int)outb[i];
}

// ---------------- MFMA input GEMM: C[M x 64] = A[M x 512] @ B[512 x 64] + bias ----------------

__global__ __launch_bounds__(256) void gemm_in_mfma(const float* __restrict__ A,
                                                    const float* __restrict__ B,
                                                    const float* __restrict__ bias,
                                                    float* __restrict__ C, int M) {
    __shared__ _Float16 As[2][64][40];
    __shared__ _Float16 Bt[2][64][40];
    int t = threadIdx.x;
    int lane = t & 63;
    int wid = t >> 6;
    int row0 = blockIdx.x * 64;

    floatx4 acc[4];
#pragma unroll
    for (int ct = 0; ct < 4; ++ct) acc[ct] = (floatx4){0.f, 0.f, 0.f, 0.f};

#define STAGE_A(buf, kt)                                                           \
    {                                                                              \
        int r = t >> 2, kq = (t & 3) << 3;                                         \
        int gr = row0 + r;                                                         \
        float4 v0 = make_float4(0.f, 0.f, 0.f, 0.f), v1 = v0;                      \
        if (gr < M) {                                                              \
            v0 = *(const float4*)&A[(size_t)gr * 512 + (kt) * 32 + kq];            \
            v1 = *(const float4*)&A[(size_t)gr * 512 + (kt) * 32 + kq + 4];        \
        }                                                                          \
        half8 h;                                                                   \
        h[0] = (_Float16)v0.x; h[1] = (_Float16)v0.y;                              \
        h[2] = (_Float16)v0.z; h[3] = (_Float16)v0.w;                              \
        h[4] = (_Float16)v1.x; h[5] = (_Float16)v1.y;                              \
        h[6] = (_Float16)v1.z; h[7] = (_Float16)v1.w;                              \
        *(half8*)&As[buf][r][kq] = h;                                              \
    }

#define STAGE_B(buf, kt)                                                           \
    {                                                                              \
        int k = t >> 3, n0 = (t & 7) << 3;                                         \
        float4 w0 = *(const float4*)&B[(size_t)((kt) * 32 + k) * 64 + n0];         \
        float4 w1 = *(const float4*)&B[(size_t)((kt) * 32 + k) * 64 + n0 + 4];     \
        Bt[buf][n0 + 0][k] = (_Float16)w0.x; Bt[buf][n0 + 1][k] = (_Float16)w0.y;  \
        Bt[buf][n0 + 2][k] = (_Float16)w0.z; Bt[buf][n0 + 3][k] = (_Float16)w0.w;  \
        Bt[buf][n0 + 4][k] = (_Float16)w1.x; Bt[buf][n0 + 5][k] = (_Float16)w1.y;  \
        Bt[buf][n0 + 6][k] = (_Float16)w1.z; Bt[buf][n0 + 7][k] = (_Float16)w1.w;  \
    }

    STAGE_A(0, 0)
    STAGE_B(0, 0)
    __syncthreads();
    for (int kt = 0; kt < 16; ++kt) {
        int buf = kt & 1;
        if (kt < 15) {
            STAGE_A(buf ^ 1, kt + 1)
            STAGE_B(buf ^ 1, kt + 1)
        }
        half8 a = *(half8*)&As[buf][wid * 16 + (lane & 15)][(lane >> 4) * 8];
#pragma unroll
        for (int ct = 0; ct < 4; ++ct) {
            half8 b = *(half8*)&Bt[buf][ct * 16 + (lane & 15)][(lane >> 4) * 8];
            acc[ct] = __builtin_amdgcn_mfma_f32_16x16x32_f16(a, b, acc[ct], 0, 0, 0);
        }
        __syncthreads();
    }
#pragma unroll
    for (int ct = 0; ct < 4; ++ct) {
        int colg = ct * 16 + (lane & 15);
        float bv = bias[colg];
#pragma unroll
        for (int i = 0; i < 4; ++i) {
            int gr = row0 + wid * 16 + (lane >> 4) * 4 + i;
            if (gr < M) C[(size_t)gr * 64 + colg] = acc[ct][i] + bv;
        }
    }
#undef STAGE_A
#undef STAGE_B
}

// ---------------- MFMA fused layer GEMM: h2 = A @ W  + att dots + fp16 store ----------------

__global__ __launch_bounds__(256) void gemm_fused_mfma(const float* __restrict__ A,
                                                       const float* __restrict__ W,
                                                       const float* __restrict__ att_s_g,
                                                       const float* __restrict__ att_d_g,
                                                       float* __restrict__ as_,
                                                       float* __restrict__ ad_,
                                                       __half* __restrict__ h2h, int M) {
    __shared__ _Float16 As[64][72];
    __shared__ _Float16 Wt[64][72];
    __shared__ float sATT[128];
    int t = threadIdx.x;
    int lane = t & 63;
    int wid = t >> 6;
    int row0 = blockIdx.x * 64;
    if (t < 128) sATT[t] = (t < 64) ? att_s_g[t] : att_d_g[t - 64];

    {
        int r = t >> 2, kq = (t & 3) << 4;
        int gr = row0 + r;
        float4 v0 = make_float4(0.f, 0.f, 0.f, 0.f), v1 = v0, v2 = v0, v3 = v0;
        if (gr < M) {
            const float* ap = &A[(size_t)gr * 64 + kq];
            v0 = *(const float4*)(ap + 0);
            v1 = *(const float4*)(ap + 4);
            v2 = *(const float4*)(ap + 8);
            v3 = *(const float4*)(ap + 12);
        }
        half8 h0, h1;
        h0[0] = (_Float16)v0.x; h0[1] = (_Float16)v0.y; h0[2] = (_Float16)v0.z; h0[3] = (_Float16)v0.w;
        h0[4] = (_Float16)v1.x; h0[5] = (_Float16)v1.y; h0[6] = (_Float16)v1.z; h0[7] = (_Float16)v1.w;
        h1[0] = (_Float16)v2.x; h1[1] = (_Float16)v2.y; h1[2] = (_Float16)v2.z; h1[3] = (_Float16)v2.w;
        h1[4] = (_Float16)v3.x; h1[5] = (_Float16)v3.y; h1[6] = (_Float16)v3.z; h1[7] = (_Float16)v3.w;
        *(half8*)&As[r][kq] = h0;
        *(half8*)&As[r][kq + 8] = h1;
    }
    {
        int k = t >> 2, n0 = (t & 3) << 4;
        const float* wp = &W[(size_t)k * 64 + n0];
        float4 w0 = *(const float4*)(wp + 0);
        float4 w1 = *(const float4*)(wp + 4);
        float4 w2 = *(const float4*)(wp + 8);
        float4 w3 = *(const float4*)(wp + 12);
        float wv[16] = {w0.x, w0.y, w0.z, w0.w, w1.x, w1.y, w1.z, w1.w,
                        w2.x, w2.y, w2.z, w2.w, w3.x, w3.y, w3.z, w3.w};
#pragma unroll
        for (int j = 0; j < 16; ++j) Wt[n0 + j][k] = (_Float16)wv[j];
    }
    __syncthreads();

    floatx4 acc[4];
#pragma unroll
    for (int ct = 0; ct < 4; ++ct) acc[ct] = (floatx4){0.f, 0.f, 0.f, 0.f};
#pragma unroll
    for (int kt = 0; kt < 2; ++kt) {
        half8 a = *(half8*)&As[wid * 16 + (lane & 15)][kt * 32 + (lane >> 4) * 8];
#pragma unroll
        for (int ct = 0; ct < 4; ++ct) {
            half8 b = *(half8*)&Wt[ct * 16 + (lane & 15)][kt * 32 + (lane >> 4) * 8];
            acc[ct] = __builtin_amdgcn_mfma_f32_16x16x32_f16(a, b, acc[ct], 0, 0, 0);
        }
    }

    int c15 = lane & 15;
    float ps[4] = {0.f, 0.f, 0.f, 0.f}, pd[4] = {0.f, 0.f, 0.f, 0.f};
#pragma unroll
    for (int ct = 0; ct < 4; ++ct) {
        float sa = sATT[ct * 16 + c15];
        float sd = sATT[64 + ct * 16 + c15];
#pragma unroll
        for (int i = 0; i < 4; ++i) {
            ps[i] += acc[ct][i] * sa;
            pd[i] += acc[ct][i] * sd;
        }
    }
#pragma unroll
    for (int off = 1; off < 16; off <<= 1) {
#pragma unroll
        for (int i = 0; i < 4; ++i) {
            ps[i] += __shfl_xor(ps[i], off);
            pd[i] += __shfl_xor(pd[i], off);
        }
    }
    if (c15 == 0) {
#pragma unroll
        for (int i = 0; i < 4; ++i) {
            int gr = row0 + wid * 16 + (lane >> 4) * 4 + i;
            if (gr < M) { as_[gr] = ps[i]; ad_[gr] = pd[i]; }
        }
    }
#pragma unroll
    for (int ct = 0; ct < 4; ++ct) {
        int colg = ct * 16 + c15;
#pragma unroll
        for (int i = 0; i < 4; ++i) {
            int gr = row0 + wid * 16 + (lane >> 4) * 4 + i;
            if (gr < M) h2h[(size_t)gr * 64 + colg] = __float2half(acc[ct][i]);
        }
    }
}

// ---------------- GAT aggregation: LDS-broadcast weights, fixed ref point ----------------
// (round-12 verified-fastest form: one wave per node, 8-deep full-row gathers)

__global__ __launch_bounds__(256) void gat_aggregate(const int* __restrict__ rp,
                                                     const int* __restrict__ col,
                                                     const __half* __restrict__ h2h,
                                                     const float* __restrict__ as_,
                                                     const float* __restrict__ ad_,
                                                     const float* __restrict__ bias,
                                                     float* __restrict__ h /* in/out */) {
    __shared__ int2 sw[4][64];   // per-wave (src, w-bits) staging
    int wv = threadIdx.x >> 6;
    int wid = blockIdx.x * 4 + wv;
    int lane = threadIdx.x & 63;
    if (wid >= N_NODES) return;
    int beg = rp[wid];
    int end = rp[wid + 1];
    float adv = ad_[wid];
    float m = leaky(as_[wid] + adv);   // fixed reference point

    float acc = __half2float(h2h[(size_t)wid * 64 + lane]);   // self, w = 1
    float wsum = 0.f;

    for (int j0 = beg; j0 < end; j0 += 64) {
        int rem = end - j0;
        int cnt = rem < 64 ? rem : 64;
        if (lane < cnt) {
            int s = col[j0 + lane];
            float w = __expf(leaky(as_[s] + adv) - m);
            wsum += w;
            sw[wv][lane] = make_int2(s, __float_as_int(w));
        }
        int j = 0;
        for (; j + 8 <= cnt; j += 8) {
            int2 p[8];
#pragma unroll
            for (int q = 0; q < 8; ++q) p[q] = sw[wv][j + q];   // LDS broadcast
            __half hv[8];
#pragma unroll
            for (int q = 0; q < 8; ++q) hv[q] = h2h[(size_t)p[q].x * 64 + lane];
#pragma unroll
            for (int q = 0; q < 8; ++q)
                acc = fmaf(__int_as_float(p[q].y), __half2float(hv[q]), acc);
        }
        for (; j < cnt; ++j) {
            int2 p = sw[wv][j];
            acc = fmaf(__int_as_float(p.y),
                       __half2float(h2h[(size_t)p.x * 64 + lane]), acc);
        }
    }
#pragma unroll
    for (int off = 32; off; off >>= 1) wsum += __shfl_xor(wsum, off);
    float denom = wsum + 1.0f;   // self weight exp(0)

    float o = acc / denom + bias[lane];
    float e = (o > 0.f) ? o : expm1f(o);
    size_t idx = (size_t)wid * 64 + lane;
    h[idx] = h[idx] + e;
}

// ---------------- output GEMM: out[N x 40] = h[N x 64] @ W[64 x 40] + b ----------------

__global__ __launch_bounds__(256) void out_gemm(const float* __restrict__ h,
                                                const float* __restrict__ W,
                                                const float* __restrict__ b,
                                                float* __restrict__ out) {
    __shared__ float Ws[64 * 40];
    __shared__ float bs[40];
    int t = threadIdx.x;
    for (int idx = t; idx < 64 * 40; idx += 256) Ws[idx] = W[idx];
    if (t < 40) bs[t] = b[t];
    __syncthreads();
    int wid = blockIdx.x * (blockDim.x >> 6) + (t >> 6);
    int lane = t & 63;
    if (wid >= N_NODES) return;
    float hv = h[(size_t)wid * 64 + lane];
    float acc = (lane < 40) ? bs[lane] : 0.f;
#pragma unroll
    for (int k = 0; k < 64; ++k) {
        float hk = __shfl(hv, k);
        float wv = (lane < 40) ? Ws[k * 40 + lane] : 0.f;
        acc += hk * wv;
    }
    if (lane < 40) out[(size_t)wid * 40 + lane] = acc;
}

// ---------------- launcher ----------------

extern "C" void kernel_launch(void* const* d_in, const int* in_sizes, int n_in,
                              void* d_out, int out_size, void* d_ws, size_t ws_size,
                              hipStream_t stream) {
    const float* x        = (const float*)d_in[0];
    const int* ei         = (const int*)d_in[1];
    const float* W_in     = (const float*)d_in[2];
    const float* b_in     = (const float*)d_in[3];
    const float* W_conv   = (const float*)d_in[4];
    const float* att_src  = (const float*)d_in[5];
    const float* att_dst  = (const float*)d_in[6];
    const float* b_conv   = (const float*)d_in[7];
    const float* W_out    = (const float*)d_in[8];
    const float* b_out    = (const float*)d_in[9];
    float* out = (float*)d_out;

    char* w = (char*)d_ws;
    float*    hA    = (float*)w;    w += (size_t)N_NODES * 64 * 4;
    __half*   h2h   = (__half*)w;   w += (size_t)N_NODES * 64 * 2;
    float*    as_   = (float*)w;    w += (size_t)N_NODES * 4;
    float*    ad_   = (float*)w;    w += (size_t)N_NODES * 4;
    int*      rp    = (int*)w;      w += 400016;
    int*      scur2 = (int*)w;      w += NB2 * SCUR_PAD * 4;
    int*      bbase = (int*)w;      w += 4096;
    int*      col   = (int*)w;      w += (size_t)N_EDGES * 4;
    unsigned* pairs2= (unsigned*)w; w += (size_t)NB2 * CAP2 * 4;

    // CSR build (single-level 391-bucket partition)
    zero_counters_kernel<<<(NCOUNT + 255) / 256, 256, 0, stream>>>(scur2);
    partition_direct_kernel<<<PBLOCKS, 256, 0, stream>>>(ei, scur2, pairs2);
    scan_buckets_kernel<<<1, 512, 0, stream>>>(scur2, bbase);
    bucket_sort_kernel<<<NB2, 256, 0, stream>>>(scur2, bbase, pairs2, col, rp);

    // input transform (MFMA)
    gemm_in_mfma<<<(N_NODES + 63) / 64, 256, 0, stream>>>(x, W_in, b_in, hA, N_NODES);

    for (int l = 0; l < N_LAYERS; ++l) {
        gemm_fused_mfma<<<(N_NODES + 63) / 64, 256, 0, stream>>>(hA, W_conv + (size_t)l * 64 * 64,
                                                                 att_src + l * 64, att_dst + l * 64,
                                                                 as_, ad_, h2h, N_NODES);
        gat_aggregate<<<N_NODES / 4, 256, 0, stream>>>(rp, col, h2h, as_, ad_,
                                                       b_conv + l * 64, hA);
    }

    out_gemm<<<N_NODES / 4, 256, 0, stream>>>(hA, W_out, b_out, out);
}

// Round 15
// 523.021 us; speedup vs baseline: 1.5072x; 1.1699x over previous
//
#include <hip/hip_runtime.h>
#include <hip/hip_bf16.h>
#include <hip/hip_fp16.h>

#define N_NODES 100000
#define N_EDGES 3200000
#define NFEAT 512
#define HDIM 64
#define NCLASS 40
#define N_LAYERS 4
#define NEG_SLOPE 0.2f

#define BATCH 4096                  // edges per partition block
#define PBLOCKS ((N_EDGES + BATCH - 1) / BATCH)   // 782
#define SCUR_PAD 16                 // counters on separate 64B lines

#define NB2 ((N_NODES + 255) / 256) // 391 buckets of 256 nodes
#define CAP2 9216                   // per-bucket capacity
#define NCOUNT (NB2 * SCUR_PAD)     // ints to zero

typedef __attribute__((ext_vector_type(8))) _Float16 half8;
typedef __attribute__((ext_vector_type(4))) float floatx4;

__device__ __forceinline__ float leaky(float x) {
    return x >= 0.f ? x : NEG_SLOPE * x;
}

__global__ void zero_counters_kernel(int* __restrict__ p) {
    int i = blockIdx.x * blockDim.x + threadIdx.x;
    if (i < NCOUNT) p[i] = 0;
}

// ---------------- CSR build: single-level 391-bucket partition ----------------

__global__ __launch_bounds__(256) void partition_direct_kernel(const int* __restrict__ ei,
                                                               int* __restrict__ scur2,
                                                               unsigned* __restrict__ pairs2) {
    __shared__ unsigned buf[BATCH];
    __shared__ int cnt[NB2];
    __shared__ int off[NB2 + 1];
    __shared__ int gb[NB2];
    int t = threadIdx.x;
    long long base = (long long)blockIdx.x * BATCH;

    unsigned key[16];
    int bn[16];
    for (int i = t; i < NB2; i += 256) cnt[i] = 0;
    __syncthreads();

#pragma unroll
    for (int i = 0; i < 16; ++i) {
        long long e = base + i * 256 + t;
        if (e < N_EDGES) {
            int s = ei[e];
            int d = ei[N_EDGES + e];
            int b = d >> 8;
            bn[i] = b;
            key[i] = (unsigned)s | ((unsigned)(d & 255) << 17);
            atomicAdd(&cnt[b], 1);
        } else {
            bn[i] = -1;
        }
    }
    __syncthreads();
    if (t == 0) {
        int run = 0;
        for (int s2 = 0; s2 < NB2; ++s2) { off[s2] = run; run += cnt[s2]; }
        off[NB2] = run;
    }
    __syncthreads();
    for (int i = t; i < NB2; i += 256) {
        int c = cnt[i];
        gb[i] = c ? atomicAdd(&scur2[i * SCUR_PAD], c) : 0;
        cnt[i] = 0;
    }
    __syncthreads();
#pragma unroll
    for (int i = 0; i < 16; ++i) {
        if (bn[i] >= 0) {
            int p = atomicAdd(&cnt[bn[i]], 1);
            buf[off[bn[i]] + p] = key[i];
        }
    }
    __syncthreads();
    int total = off[NB2];
    for (int p = t; p < total; p += 256) {
        int lo = 0, hi = NB2 - 1;
        while (lo < hi) {
            int mid = (lo + hi + 1) >> 1;
            if (off[mid] <= p) lo = mid; else hi = mid - 1;
        }
        int idx = gb[lo] + (p - off[lo]);
        if (idx < CAP2) pairs2[(size_t)lo * CAP2 + idx] = buf[p];
    }
}

__global__ __launch_bounds__(512) void scan_buckets_kernel(const int* __restrict__ scur2,
                                                           int* __restrict__ bbase) {
    __shared__ int s[512];
    int t = threadIdx.x;
    int v = 0;
    if (t < NB2) {
        v = scur2[t * SCUR_PAD];
        if (v > CAP2) v = CAP2;
    }
    s[t] = v;
    __syncthreads();
    for (int off = 1; off < 512; off <<= 1) {
        int x = (t >= off) ? s[t - off] : 0;
        __syncthreads();
        s[t] += x;
        __syncthreads();
    }
    if (t < NB2) bbase[t] = s[t] - v;
    if (t == NB2 - 1) bbase[NB2] = s[t];
}

__global__ __launch_bounds__(256) void bucket_sort_kernel(const int* __restrict__ scur2,
                                                          const int* __restrict__ bbase,
                                                          const unsigned* __restrict__ pairs2,
                                                          int* __restrict__ col,
                                                          int* __restrict__ rp) {
    __shared__ int hist[256];
    __shared__ int cur[256];
    __shared__ unsigned outb[CAP2];
    int b = blockIdx.x;
    int c = scur2[b * SCUR_PAD]; if (c > CAP2) c = CAP2;
    const unsigned* seg = pairs2 + (size_t)b * CAP2;
    int t = threadIdx.x;
    int nlo = b * 256;
    int nnodes = N_NODES - nlo; if (nnodes > 256) nnodes = 256;
    hist[t] = 0;
    __syncthreads();
    for (int i = t; i < c; i += 256) atomicAdd(&hist[(seg[i] >> 17) & 255], 1);
    __syncthreads();
    int v = hist[t];
    for (int off = 1; off < 256; off <<= 1) {
        int x = (t >= off) ? hist[t - off] : 0;
        __syncthreads();
        hist[t] += x;
        __syncthreads();
    }
    int excl = hist[t] - v;
    cur[t] = excl;
    int base = bbase[b];
    if (t < nnodes) rp[nlo + t] = base + excl;
    if (b == NB2 - 1 && t == 0) rp[N_NODES] = base + c;
    __syncthreads();
    for (int i = t; i < c; i += 256) {
        unsigned k = seg[i];
        int p = atomicAdd(&cur[(k >> 17) & 255], 1);
        outb[p] = k & 0x1FFFFu;
    }
    __syncthreads();
    for (int i = t; i < c; i += 256) col[base + i] = (int)outb[i];
}

// ---------------- MFMA input GEMM: C[M x 64] = A[M x 512] @ B[512 x 64] + bias ----------------

__global__ __launch_bounds__(256) void gemm_in_mfma(const float* __restrict__ A,
                                                    const float* __restrict__ B,
                                                    const float* __restrict__ bias,
                                                    float* __restrict__ C, int M) {
    __shared__ _Float16 As[2][64][40];
    __shared__ _Float16 Bt[2][64][40];
    int t = threadIdx.x;
    int lane = t & 63;
    int wid = t >> 6;
    int row0 = blockIdx.x * 64;

    floatx4 acc[4];
#pragma unroll
    for (int ct = 0; ct < 4; ++ct) acc[ct] = (floatx4){0.f, 0.f, 0.f, 0.f};

#define STAGE_A(buf, kt)                                                           \
    {                                                                              \
        int r = t >> 2, kq = (t & 3) << 3;                                         \
        int gr = row0 + r;                                                         \
        float4 v0 = make_float4(0.f, 0.f, 0.f, 0.f), v1 = v0;                      \
        if (gr < M) {                                                              \
            v0 = *(const float4*)&A[(size_t)gr * 512 + (kt) * 32 + kq];            \
            v1 = *(const float4*)&A[(size_t)gr * 512 + (kt) * 32 + kq + 4];        \
        }                                                                          \
        half8 h;                                                                   \
        h[0] = (_Float16)v0.x; h[1] = (_Float16)v0.y;                              \
        h[2] = (_Float16)v0.z; h[3] = (_Float16)v0.w;                              \
        h[4] = (_Float16)v1.x; h[5] = (_Float16)v1.y;                              \
        h[6] = (_Float16)v1.z; h[7] = (_Float16)v1.w;                              \
        *(half8*)&As[buf][r][kq] = h;                                              \
    }

#define STAGE_B(buf, kt)                                                           \
    {                                                                              \
        int k = t >> 3, n0 = (t & 7) << 3;                                         \
        float4 w0 = *(const float4*)&B[(size_t)((kt) * 32 + k) * 64 + n0];         \
        float4 w1 = *(const float4*)&B[(size_t)((kt) * 32 + k) * 64 + n0 + 4];     \
        Bt[buf][n0 + 0][k] = (_Float16)w0.x; Bt[buf][n0 + 1][k] = (_Float16)w0.y;  \
        Bt[buf][n0 + 2][k] = (_Float16)w0.z; Bt[buf][n0 + 3][k] = (_Float16)w0.w;  \
        Bt[buf][n0 + 4][k] = (_Float16)w1.x; Bt[buf][n0 + 5][k] = (_Float16)w1.y;  \
        Bt[buf][n0 + 6][k] = (_Float16)w1.z; Bt[buf][n0 + 7][k] = (_Float16)w1.w;  \
    }

    STAGE_A(0, 0)
    STAGE_B(0, 0)
    __syncthreads();
    for (int kt = 0; kt < 16; ++kt) {
        int buf = kt & 1;
        if (kt < 15) {
            STAGE_A(buf ^ 1, kt + 1)
            STAGE_B(buf ^ 1, kt + 1)
        }
        half8 a = *(half8*)&As[buf][wid * 16 + (lane & 15)][(lane >> 4) * 8];
#pragma unroll
        for (int ct = 0; ct < 4; ++ct) {
            half8 b = *(half8*)&Bt[buf][ct * 16 + (lane & 15)][(lane >> 4) * 8];
            acc[ct] = __builtin_amdgcn_mfma_f32_16x16x32_f16(a, b, acc[ct], 0, 0, 0);
        }
        __syncthreads();
    }
#pragma unroll
    for (int ct = 0; ct < 4; ++ct) {
        int colg = ct * 16 + (lane & 15);
        float bv = bias[colg];
#pragma unroll
        for (int i = 0; i < 4; ++i) {
            int gr = row0 + wid * 16 + (lane >> 4) * 4 + i;
            if (gr < M) C[(size_t)gr * 64 + colg] = acc[ct][i] + bv;
        }
    }
#undef STAGE_A
#undef STAGE_B
}

// ---------------- MFMA fused layer GEMM: h2 = A @ W  + att dots + fp16 store ----------------

__global__ __launch_bounds__(256) void gemm_fused_mfma(const float* __restrict__ A,
                                                       const float* __restrict__ W,
                                                       const float* __restrict__ att_s_g,
                                                       const float* __restrict__ att_d_g,
                                                       float* __restrict__ as_,
                                                       float* __restrict__ ad_,
                                                       __half* __restrict__ h2h, int M) {
    __shared__ _Float16 As[64][72];
    __shared__ _Float16 Wt[64][72];
    __shared__ float sATT[128];
    int t = threadIdx.x;
    int lane = t & 63;
    int wid = t >> 6;
    int row0 = blockIdx.x * 64;
    if (t < 128) sATT[t] = (t < 64) ? att_s_g[t] : att_d_g[t - 64];

    {
        int r = t >> 2, kq = (t & 3) << 4;
        int gr = row0 + r;
        float4 v0 = make_float4(0.f, 0.f, 0.f, 0.f), v1 = v0, v2 = v0, v3 = v0;
        if (gr < M) {
            const float* ap = &A[(size_t)gr * 64 + kq];
            v0 = *(const float4*)(ap + 0);
            v1 = *(const float4*)(ap + 4);
            v2 = *(const float4*)(ap + 8);
            v3 = *(const float4*)(ap + 12);
        }
        half8 h0, h1;
        h0[0] = (_Float16)v0.x; h0[1] = (_Float16)v0.y; h0[2] = (_Float16)v0.z; h0[3] = (_Float16)v0.w;
        h0[4] = (_Float16)v1.x; h0[5] = (_Float16)v1.y; h0[6] = (_Float16)v1.z; h0[7] = (_Float16)v1.w;
        h1[0] = (_Float16)v2.x; h1[1] = (_Float16)v2.y; h1[2] = (_Float16)v2.z; h1[3] = (_Float16)v2.w;
        h1[4] = (_Float16)v3.x; h1[5] = (_Float16)v3.y; h1[6] = (_Float16)v3.z; h1[7] = (_Float16)v3.w;
        *(half8*)&As[r][kq] = h0;
        *(half8*)&As[r][kq + 8] = h1;
    }
    {
        int k = t >> 2, n0 = (t & 3) << 4;
        const float* wp = &W[(size_t)k * 64 + n0];
        float4 w0 = *(const float4*)(wp + 0);
        float4 w1 = *(const float4*)(wp + 4);
        float4 w2 = *(const float4*)(wp + 8);
        float4 w3 = *(const float4*)(wp + 12);
        float wv[16] = {w0.x, w0.y, w0.z, w0.w, w1.x, w1.y, w1.z, w1.w,
                        w2.x, w2.y, w2.z, w2.w, w3.x, w3.y, w3.z, w3.w};
#pragma unroll
        for (int j = 0; j < 16; ++j) Wt[n0 + j][k] = (_Float16)wv[j];
    }
    __syncthreads();

    floatx4 acc[4];
#pragma unroll
    for (int ct = 0; ct < 4; ++ct) acc[ct] = (floatx4){0.f, 0.f, 0.f, 0.f};
#pragma unroll
    for (int kt = 0; kt < 2; ++kt) {
        half8 a = *(half8*)&As[wid * 16 + (lane & 15)][kt * 32 + (lane >> 4) * 8];
#pragma unroll
        for (int ct = 0; ct < 4; ++ct) {
            half8 b = *(half8*)&Wt[ct * 16 + (lane & 15)][kt * 32 + (lane >> 4) * 8];
            acc[ct] = __builtin_amdgcn_mfma_f32_16x16x32_f16(a, b, acc[ct], 0, 0, 0);
        }
    }

    int c15 = lane & 15;
    float ps[4] = {0.f, 0.f, 0.f, 0.f}, pd[4] = {0.f, 0.f, 0.f, 0.f};
#pragma unroll
    for (int ct = 0; ct < 4; ++ct) {
        float sa = sATT[ct * 16 + c15];
        float sd = sATT[64 + ct * 16 + c15];
#pragma unroll
        for (int i = 0; i < 4; ++i) {
            ps[i] += acc[ct][i] * sa;
            pd[i] += acc[ct][i] * sd;
        }
    }
#pragma unroll
    for (int off = 1; off < 16; off <<= 1) {
#pragma unroll
        for (int i = 0; i < 4; ++i) {
            ps[i] += __shfl_xor(ps[i], off);
            pd[i] += __shfl_xor(pd[i], off);
        }
    }
    if (c15 == 0) {
#pragma unroll
        for (int i = 0; i < 4; ++i) {
            int gr = row0 + wid * 16 + (lane >> 4) * 4 + i;
            if (gr < M) { as_[gr] = ps[i]; ad_[gr] = pd[i]; }
        }
    }
#pragma unroll
    for (int ct = 0; ct < 4; ++ct) {
        int colg = ct * 16 + c15;
#pragma unroll
        for (int i = 0; i < 4; ++i) {
            int gr = row0 + wid * 16 + (lane >> 4) * 4 + i;
            if (gr < M) h2h[(size_t)gr * 64 + colg] = __float2half(acc[ct][i]);
        }
    }
}

// ---------------- GAT aggregation: dual-node per wave, LDS staging ----------------
// One wave processes nodes (2g, 2g+1): their CSR ranges are contiguous, so the
// combined ~66-edge stream halves staging/tail/reduction overhead per node.
// acc0/acc1 selection uses the WAVE-UNIFORM comparison (edge index < mid):
// scalar branch, no divergence. Full-row gathers kept (round-13 lesson).
// FUSE_OUT: layer-4 variant computes out = h @ W_out + b_out in the epilogue
// (h row staged to wave-local LDS; 40 lanes do the 64-deep dot), skipping the
// hA write and the separate out_gemm pass.

template <bool FUSE_OUT>
__global__ __launch_bounds__(256) void gat_aggregate_t(const int* __restrict__ rp,
                                                       const int* __restrict__ col,
                                                       const __half* __restrict__ h2h,
                                                       const float* __restrict__ as_,
                                                       const float* __restrict__ ad_,
                                                       const float* __restrict__ bias,
                                                       float* __restrict__ h,
                                                       const float* __restrict__ W_out,
                                                       const float* __restrict__ b_out,
                                                       float* __restrict__ out) {
    __shared__ int2 sw[4][64];       // per-wave (src, w-bits) staging
    __shared__ float sh[4][64];      // per-wave h-row staging (FUSE_OUT)
    __shared__ float Ws[64 * 40];    // W_out (FUSE_OUT)
    __shared__ float bs[40];
    int t = threadIdx.x;
    int wv = t >> 6;
    int lane = t & 63;
    if (FUSE_OUT) {
        for (int i = t; i < 64 * 40; i += 256) Ws[i] = W_out[i];
        if (t < 40) bs[t] = b_out[t];
        __syncthreads();             // grid is exact (no early-exit waves)
    }
    int n0 = (blockIdx.x * 4 + wv) * 2;

    int beg = rp[n0];
    int mid = rp[n0 + 1];
    int end = rp[n0 + 2];
    float adv0 = ad_[n0], adv1 = ad_[n0 + 1];
    float m0 = leaky(as_[n0] + adv0);
    float m1 = leaky(as_[n0 + 1] + adv1);

    float acc0 = __half2float(h2h[(size_t)n0 * 64 + lane]);        // self, w=1
    float acc1 = __half2float(h2h[(size_t)(n0 + 1) * 64 + lane]);
    float wsum0 = 0.f, wsum1 = 0.f;

    for (int j0 = beg; j0 < end; j0 += 64) {
        int rem = end - j0;
        int cnt = rem < 64 ? rem : 64;
        if (lane < cnt) {
            int j = j0 + lane;
            int s = col[j];
            bool is1 = (j >= mid);
            float adv = is1 ? adv1 : adv0;
            float m = is1 ? m1 : m0;
            float w = __expf(leaky(as_[s] + adv) - m);
            if (is1) wsum1 += w; else wsum0 += w;
            sw[wv][lane] = make_int2(s, __float_as_int(w));
        }
        int j = 0;
        for (; j + 8 <= cnt; j += 8) {
            int2 p[8];
#pragma unroll
            for (int q = 0; q < 8; ++q) p[q] = sw[wv][j + q];   // LDS broadcast
            __half hv[8];
#pragma unroll
            for (int q = 0; q < 8; ++q) hv[q] = h2h[(size_t)p[q].x * 64 + lane];
#pragma unroll
            for (int q = 0; q < 8; ++q) {
                float w = __int_as_float(p[q].y);
                float v = __half2float(hv[q]);
                if (j0 + j + q < mid) acc0 = fmaf(w, v, acc0);   // uniform branch
                else                  acc1 = fmaf(w, v, acc1);
            }
        }
        for (; j < cnt; ++j) {
            int2 p = sw[wv][j];
            float w = __int_as_float(p.y);
            float v = __half2float(h2h[(size_t)p.x * 64 + lane]);
            if (j0 + j < mid) acc0 = fmaf(w, v, acc0);
            else              acc1 = fmaf(w, v, acc1);
        }
    }
#pragma unroll
    for (int off = 32; off; off >>= 1) {
        wsum0 += __shfl_xor(wsum0, off);
        wsum1 += __shfl_xor(wsum1, off);
    }
    float bv = bias[lane];
    float o0 = acc0 / (wsum0 + 1.0f) + bv;
    float o1 = acc1 / (wsum1 + 1.0f) + bv;
    float e0 = (o0 > 0.f) ? o0 : expm1f(o0);
    float e1 = (o1 > 0.f) ? o1 : expm1f(o1);
    float h0 = h[(size_t)n0 * 64 + lane] + e0;        // residual
    float h1 = h[(size_t)(n0 + 1) * 64 + lane] + e1;

    if constexpr (!FUSE_OUT) {
        h[(size_t)n0 * 64 + lane] = h0;
        h[(size_t)(n0 + 1) * 64 + lane] = h1;
    } else {
        // out = h_row @ W_out + b_out, per node (wave-local LDS broadcast dot)
        sw[wv][lane] = make_int2(0, 0);   // keep sw live-range closed
        sh[wv][lane] = h0;
        float o = (lane < 40) ? bs[lane] : 0.f;
#pragma unroll 8
        for (int k = 0; k < 64; ++k)
            o = fmaf(sh[wv][k], (lane < 40) ? Ws[k * 40 + lane] : 0.f, o);
        if (lane < 40) out[(size_t)n0 * 40 + lane] = o;

        sh[wv][lane] = h1;
        float o2 = (lane < 40) ? bs[lane] : 0.f;
#pragma unroll 8
        for (int k = 0; k < 64; ++k)
            o2 = fmaf(sh[wv][k], (lane < 40) ? Ws[k * 40 + lane] : 0.f, o2);
        if (lane < 40) out[(size_t)(n0 + 1) * 40 + lane] = o2;
    }
}

// ---------------- launcher ----------------

extern "C" void kernel_launch(void* const* d_in, const int* in_sizes, int n_in,
                              void* d_out, int out_size, void* d_ws, size_t ws_size,
                              hipStream_t stream) {
    const float* x        = (const float*)d_in[0];
    const int* ei         = (const int*)d_in[1];
    const float* W_in     = (const float*)d_in[2];
    const float* b_in     = (const float*)d_in[3];
    const float* W_conv   = (const float*)d_in[4];
    const float* att_src  = (const float*)d_in[5];
    const float* att_dst  = (const float*)d_in[6];
    const float* b_conv   = (const float*)d_in[7];
    const float* W_out    = (const float*)d_in[8];
    const float* b_out    = (const float*)d_in[9];
    float* out = (float*)d_out;

    char* w = (char*)d_ws;
    float*    hA    = (float*)w;    w += (size_t)N_NODES * 64 * 4;
    __half*   h2h   = (__half*)w;   w += (size_t)N_NODES * 64 * 2;
    float*    as_   = (float*)w;    w += (size_t)N_NODES * 4;
    float*    ad_   = (float*)w;    w += (size_t)N_NODES * 4;
    int*      rp    = (int*)w;      w += 400016;
    int*      scur2 = (int*)w;      w += NB2 * SCUR_PAD * 4;
    int*      bbase = (int*)w;      w += 4096;
    int*      col   = (int*)w;      w += (size_t)N_EDGES * 4;
    unsigned* pairs2= (unsigned*)w; w += (size_t)NB2 * CAP2 * 4;

    // CSR build (single-level 391-bucket partition)
    zero_counters_kernel<<<(NCOUNT + 255) / 256, 256, 0, stream>>>(scur2);
    partition_direct_kernel<<<PBLOCKS, 256, 0, stream>>>(ei, scur2, pairs2);
    scan_buckets_kernel<<<1, 512, 0, stream>>>(scur2, bbase);
    bucket_sort_kernel<<<NB2, 256, 0, stream>>>(scur2, bbase, pairs2, col, rp);

    // input transform (MFMA)
    gemm_in_mfma<<<(N_NODES + 63) / 64, 256, 0, stream>>>(x, W_in, b_in, hA, N_NODES);

    // N_NODES/2 pairs, 4 waves per block -> exact grid (no early-exit waves)
    int agg_blocks = N_NODES / 8;   // 12500
    for (int l = 0; l < N_LAYERS; ++l) {
        gemm_fused_mfma<<<(N_NODES + 63) / 64, 256, 0, stream>>>(hA, W_conv + (size_t)l * 64 * 64,
                                                                 att_src + l * 64, att_dst + l * 64,
                                                                 as_, ad_, h2h, N_NODES);
        if (l < N_LAYERS - 1) {
            gat_aggregate_t<false><<<agg_blocks, 256, 0, stream>>>(rp, col, h2h, as_, ad_,
                                                                   b_conv + l * 64, hA,
                                                                   nullptr, nullptr, nullptr);
        } else {
            gat_aggregate_t<true><<<agg_blocks, 256, 0, stream>>>(rp, col, h2h, as_, ad_,
                                                                  b_conv + l * 64, hA,
                                                                  W_out, b_out, out);
        }
    }
}

// Round 16
// 509.234 us; speedup vs baseline: 1.5480x; 1.0271x over previous
//
#include <hip/hip_runtime.h>
#include <hip/hip_bf16.h>
#include <hip/hip_fp16.h>

#define N_NODES 100000
#define N_EDGES 3200000
#define NFEAT 512
#define HDIM 64
#define NCLASS 40
#define N_LAYERS 4
#define NEG_SLOPE 0.2f

#define BATCH 4096                  // edges per partition block
#define PBLOCKS ((N_EDGES + BATCH - 1) / BATCH)   // 782
#define SCUR_PAD 16                 // counters on separate 64B lines

#define NB2 ((N_NODES + 255) / 256) // 391 buckets of 256 nodes
#define CAP2 9216                   // per-bucket capacity
#define NCOUNT (NB2 * SCUR_PAD)     // ints to zero

typedef __attribute__((ext_vector_type(8))) _Float16 half8;
typedef __attribute__((ext_vector_type(4))) float floatx4;

__device__ __forceinline__ float leaky(float x) {
    return x >= 0.f ? x : NEG_SLOPE * x;
}

__global__ void zero_counters_kernel(int* __restrict__ p) {
    int i = blockIdx.x * blockDim.x + threadIdx.x;
    if (i < NCOUNT) p[i] = 0;
}

// ---------------- CSR build: single-level 391-bucket partition ----------------

__global__ __launch_bounds__(256) void partition_direct_kernel(const int* __restrict__ ei,
                                                               int* __restrict__ scur2,
                                                               unsigned* __restrict__ pairs2) {
    __shared__ unsigned buf[BATCH];
    __shared__ int cnt[NB2];
    __shared__ int off[NB2 + 1];
    __shared__ int gb[NB2];
    int t = threadIdx.x;
    long long base = (long long)blockIdx.x * BATCH;

    unsigned key[16];
    int bn[16];
    for (int i = t; i < NB2; i += 256) cnt[i] = 0;
    __syncthreads();

#pragma unroll
    for (int i = 0; i < 16; ++i) {
        long long e = base + i * 256 + t;
        if (e < N_EDGES) {
            int s = ei[e];
            int d = ei[N_EDGES + e];
            int b = d >> 8;
            bn[i] = b;
            key[i] = (unsigned)s | ((unsigned)(d & 255) << 17);
            atomicAdd(&cnt[b], 1);
        } else {
            bn[i] = -1;
        }
    }
    __syncthreads();
    if (t == 0) {
        int run = 0;
        for (int s2 = 0; s2 < NB2; ++s2) { off[s2] = run; run += cnt[s2]; }
        off[NB2] = run;
    }
    __syncthreads();
    for (int i = t; i < NB2; i += 256) {
        int c = cnt[i];
        gb[i] = c ? atomicAdd(&scur2[i * SCUR_PAD], c) : 0;
        cnt[i] = 0;
    }
    __syncthreads();
#pragma unroll
    for (int i = 0; i < 16; ++i) {
        if (bn[i] >= 0) {
            int p = atomicAdd(&cnt[bn[i]], 1);
            buf[off[bn[i]] + p] = key[i];
        }
    }
    __syncthreads();
    int total = off[NB2];
    for (int p = t; p < total; p += 256) {
        int lo = 0, hi = NB2 - 1;
        while (lo < hi) {
            int mid = (lo + hi + 1) >> 1;
            if (off[mid] <= p) lo = mid; else hi = mid - 1;
        }
        int idx = gb[lo] + (p - off[lo]);
        if (idx < CAP2) pairs2[(size_t)lo * CAP2 + idx] = buf[p];
    }
}

__global__ __launch_bounds__(512) void scan_buckets_kernel(const int* __restrict__ scur2,
                                                           int* __restrict__ bbase) {
    __shared__ int s[512];
    int t = threadIdx.x;
    int v = 0;
    if (t < NB2) {
        v = scur2[t * SCUR_PAD];
        if (v > CAP2) v = CAP2;
    }
    s[t] = v;
    __syncthreads();
    for (int off = 1; off < 512; off <<= 1) {
        int x = (t >= off) ? s[t - off] : 0;
        __syncthreads();
        s[t] += x;
        __syncthreads();
    }
    if (t < NB2) bbase[t] = s[t] - v;
    if (t == NB2 - 1) bbase[NB2] = s[t];
}

__global__ __launch_bounds__(256) void bucket_sort_kernel(const int* __restrict__ scur2,
                                                          const int* __restrict__ bbase,
                                                          const unsigned* __restrict__ pairs2,
                                                          int* __restrict__ col,
                                                          int* __restrict__ rp) {
    __shared__ int hist[256];
    __shared__ int cur[256];
    __shared__ unsigned outb[CAP2];
    int b = blockIdx.x;
    int c = scur2[b * SCUR_PAD]; if (c > CAP2) c = CAP2;
    const unsigned* seg = pairs2 + (size_t)b * CAP2;
    int t = threadIdx.x;
    int nlo = b * 256;
    int nnodes = N_NODES - nlo; if (nnodes > 256) nnodes = 256;
    hist[t] = 0;
    __syncthreads();
    for (int i = t; i < c; i += 256) atomicAdd(&hist[(seg[i] >> 17) & 255], 1);
    __syncthreads();
    int v = hist[t];
    for (int off = 1; off < 256; off <<= 1) {
        int x = (t >= off) ? hist[t - off] : 0;
        __syncthreads();
        hist[t] += x;
        __syncthreads();
    }
    int excl = hist[t] - v;
    cur[t] = excl;
    int base = bbase[b];
    if (t < nnodes) rp[nlo + t] = base + excl;
    if (b == NB2 - 1 && t == 0) rp[N_NODES] = base + c;
    __syncthreads();
    for (int i = t; i < c; i += 256) {
        unsigned k = seg[i];
        int p = atomicAdd(&cur[(k >> 17) & 255], 1);
        outb[p] = k & 0x1FFFFu;
    }
    __syncthreads();
    for (int i = t; i < c; i += 256) col[base + i] = (int)outb[i];
}

// ---------------- MFMA input GEMM: C[M x 64] = A[M x 512] @ B[512 x 64] + bias ----------------

__global__ __launch_bounds__(256) void gemm_in_mfma(const float* __restrict__ A,
                                                    const float* __restrict__ B,
                                                    const float* __restrict__ bias,
                                                    float* __restrict__ C, int M) {
    __shared__ _Float16 As[2][64][40];
    __shared__ _Float16 Bt[2][64][40];
    int t = threadIdx.x;
    int lane = t & 63;
    int wid = t >> 6;
    int row0 = blockIdx.x * 64;

    floatx4 acc[4];
#pragma unroll
    for (int ct = 0; ct < 4; ++ct) acc[ct] = (floatx4){0.f, 0.f, 0.f, 0.f};

#define STAGE_A(buf, kt)                                                           \
    {                                                                              \
        int r = t >> 2, kq = (t & 3) << 3;                                         \
        int gr = row0 + r;                                                         \
        float4 v0 = make_float4(0.f, 0.f, 0.f, 0.f), v1 = v0;                      \
        if (gr < M) {                                                              \
            v0 = *(const float4*)&A[(size_t)gr * 512 + (kt) * 32 + kq];            \
            v1 = *(const float4*)&A[(size_t)gr * 512 + (kt) * 32 + kq + 4];        \
        }                                                                          \
        half8 h;                                                                   \
        h[0] = (_Float16)v0.x; h[1] = (_Float16)v0.y;                              \
        h[2] = (_Float16)v0.z; h[3] = (_Float16)v0.w;                              \
        h[4] = (_Float16)v1.x; h[5] = (_Float16)v1.y;                              \
        h[6] = (_Float16)v1.z; h[7] = (_Float16)v1.w;                              \
        *(half8*)&As[buf][r][kq] = h;                                              \
    }

#define STAGE_B(buf, kt)                                                           \
    {                                                                              \
        int k = t >> 3, n0 = (t & 7) << 3;                                         \
        float4 w0 = *(const float4*)&B[(size_t)((kt) * 32 + k) * 64 + n0];         \
        float4 w1 = *(const float4*)&B[(size_t)((kt) * 32 + k) * 64 + n0 + 4];     \
        Bt[buf][n0 + 0][k] = (_Float16)w0.x; Bt[buf][n0 + 1][k] = (_Float16)w0.y;  \
        Bt[buf][n0 + 2][k] = (_Float16)w0.z; Bt[buf][n0 + 3][k] = (_Float16)w0.w;  \
        Bt[buf][n0 + 4][k] = (_Float16)w1.x; Bt[buf][n0 + 5][k] = (_Float16)w1.y;  \
        Bt[buf][n0 + 6][k] = (_Float16)w1.z; Bt[buf][n0 + 7][k] = (_Float16)w1.w;  \
    }

    STAGE_A(0, 0)
    STAGE_B(0, 0)
    __syncthreads();
    for (int kt = 0; kt < 16; ++kt) {
        int buf = kt & 1;
        if (kt < 15) {
            STAGE_A(buf ^ 1, kt + 1)
            STAGE_B(buf ^ 1, kt + 1)
        }
        half8 a = *(half8*)&As[buf][wid * 16 + (lane & 15)][(lane >> 4) * 8];
#pragma unroll
        for (int ct = 0; ct < 4; ++ct) {
            half8 b = *(half8*)&Bt[buf][ct * 16 + (lane & 15)][(lane >> 4) * 8];
            acc[ct] = __builtin_amdgcn_mfma_f32_16x16x32_f16(a, b, acc[ct], 0, 0, 0);
        }
        __syncthreads();
    }
#pragma unroll
    for (int ct = 0; ct < 4; ++ct) {
        int colg = ct * 16 + (lane & 15);
        float bv = bias[colg];
#pragma unroll
        for (int i = 0; i < 4; ++i) {
            int gr = row0 + wid * 16 + (lane >> 4) * 4 + i;
            if (gr < M) C[(size_t)gr * 64 + colg] = acc[ct][i] + bv;
        }
    }
#undef STAGE_A
#undef STAGE_B
}

// ---------------- MFMA fused layer GEMM: h2 = A @ W  + att dots + fp16 store ----------------

__global__ __launch_bounds__(256) void gemm_fused_mfma(const float* __restrict__ A,
                                                       const float* __restrict__ W,
                                                       const float* __restrict__ att_s_g,
                                                       const float* __restrict__ att_d_g,
                                                       float* __restrict__ as_,
                                                       float* __restrict__ ad_,
                                                       __half* __restrict__ h2h, int M) {
    __shared__ _Float16 As[64][72];
    __shared__ _Float16 Wt[64][72];
    __shared__ float sATT[128];
    int t = threadIdx.x;
    int lane = t & 63;
    int wid = t >> 6;
    int row0 = blockIdx.x * 64;
    if (t < 128) sATT[t] = (t < 64) ? att_s_g[t] : att_d_g[t - 64];

    {
        int r = t >> 2, kq = (t & 3) << 4;
        int gr = row0 + r;
        float4 v0 = make_float4(0.f, 0.f, 0.f, 0.f), v1 = v0, v2 = v0, v3 = v0;
        if (gr < M) {
            const float* ap = &A[(size_t)gr * 64 + kq];
            v0 = *(const float4*)(ap + 0);
            v1 = *(const float4*)(ap + 4);
            v2 = *(const float4*)(ap + 8);
            v3 = *(const float4*)(ap + 12);
        }
        half8 h0, h1;
        h0[0] = (_Float16)v0.x; h0[1] = (_Float16)v0.y; h0[2] = (_Float16)v0.z; h0[3] = (_Float16)v0.w;
        h0[4] = (_Float16)v1.x; h0[5] = (_Float16)v1.y; h0[6] = (_Float16)v1.z; h0[7] = (_Float16)v1.w;
        h1[0] = (_Float16)v2.x; h1[1] = (_Float16)v2.y; h1[2] = (_Float16)v2.z; h1[3] = (_Float16)v2.w;
        h1[4] = (_Float16)v3.x; h1[5] = (_Float16)v3.y; h1[6] = (_Float16)v3.z; h1[7] = (_Float16)v3.w;
        *(half8*)&As[r][kq] = h0;
        *(half8*)&As[r][kq + 8] = h1;
    }
    {
        int k = t >> 2, n0 = (t & 3) << 4;
        const float* wp = &W[(size_t)k * 64 + n0];
        float4 w0 = *(const float4*)(wp + 0);
        float4 w1 = *(const float4*)(wp + 4);
        float4 w2 = *(const float4*)(wp + 8);
        float4 w3 = *(const float4*)(wp + 12);
        float wv[16] = {w0.x, w0.y, w0.z, w0.w, w1.x, w1.y, w1.z, w1.w,
                        w2.x, w2.y, w2.z, w2.w, w3.x, w3.y, w3.z, w3.w};
#pragma unroll
        for (int j = 0; j < 16; ++j) Wt[n0 + j][k] = (_Float16)wv[j];
    }
    __syncthreads();

    floatx4 acc[4];
#pragma unroll
    for (int ct = 0; ct < 4; ++ct) acc[ct] = (floatx4){0.f, 0.f, 0.f, 0.f};
#pragma unroll
    for (int kt = 0; kt < 2; ++kt) {
        half8 a = *(half8*)&As[wid * 16 + (lane & 15)][kt * 32 + (lane >> 4) * 8];
#pragma unroll
        for (int ct = 0; ct < 4; ++ct) {
            half8 b = *(half8*)&Wt[ct * 16 + (lane & 15)][kt * 32 + (lane >> 4) * 8];
            acc[ct] = __builtin_amdgcn_mfma_f32_16x16x32_f16(a, b, acc[ct], 0, 0, 0);
        }
    }

    int c15 = lane & 15;
    float ps[4] = {0.f, 0.f, 0.f, 0.f}, pd[4] = {0.f, 0.f, 0.f, 0.f};
#pragma unroll
    for (int ct = 0; ct < 4; ++ct) {
        float sa = sATT[ct * 16 + c15];
        float sd = sATT[64 + ct * 16 + c15];
#pragma unroll
        for (int i = 0; i < 4; ++i) {
            ps[i] += acc[ct][i] * sa;
            pd[i] += acc[ct][i] * sd;
        }
    }
#pragma unroll
    for (int off = 1; off < 16; off <<= 1) {
#pragma unroll
        for (int i = 0; i < 4; ++i) {
            ps[i] += __shfl_xor(ps[i], off);
            pd[i] += __shfl_xor(pd[i], off);
        }
    }
    if (c15 == 0) {
#pragma unroll
        for (int i = 0; i < 4; ++i) {
            int gr = row0 + wid * 16 + (lane >> 4) * 4 + i;
            if (gr < M) { as_[gr] = ps[i]; ad_[gr] = pd[i]; }
        }
    }
#pragma unroll
    for (int ct = 0; ct < 4; ++ct) {
        int colg = ct * 16 + c15;
#pragma unroll
        for (int i = 0; i < 4; ++i) {
            int gr = row0 + wid * 16 + (lane >> 4) * 4 + i;
            if (gr < M) h2h[(size_t)gr * 64 + colg] = __float2half(acc[ct][i]);
        }
    }
}

// ---------------- GAT aggregation: dual-node per wave, 32-bit offset gathers ----------------
// Staging stores the UNSIGNED element offset (s*64) instead of the node id, so
// each gather is h2h[off + lane] in 32-bit math -> saddr-form global_load with
// one v_add_u32, instead of a 64-bit shift-add chain per edge (VALUBusy was 82%).

template <bool FUSE_OUT>
__global__ __launch_bounds__(256) void gat_aggregate_t(const int* __restrict__ rp,
                                                       const int* __restrict__ col,
                                                       const __half* __restrict__ h2h,
                                                       const float* __restrict__ as_,
                                                       const float* __restrict__ ad_,
                                                       const float* __restrict__ bias,
                                                       float* __restrict__ h,
                                                       const float* __restrict__ W_out,
                                                       const float* __restrict__ b_out,
                                                       float* __restrict__ out) {
    __shared__ int2 sw[4][64];       // per-wave (offset, w-bits) staging
    __shared__ float sh[4][64];      // per-wave h-row staging (FUSE_OUT)
    __shared__ float Ws[64 * 40];    // W_out (FUSE_OUT)
    __shared__ float bs[40];
    int t = threadIdx.x;
    int wv = t >> 6;
    int lane = t & 63;
    if (FUSE_OUT) {
        for (int i = t; i < 64 * 40; i += 256) Ws[i] = W_out[i];
        if (t < 40) bs[t] = b_out[t];
        __syncthreads();             // grid is exact (no early-exit waves)
    }
    int n0 = (blockIdx.x * 4 + wv) * 2;

    int beg = rp[n0];
    int mid = rp[n0 + 1];
    int end = rp[n0 + 2];
    float adv0 = ad_[n0], adv1 = ad_[n0 + 1];
    float m0 = leaky(as_[n0] + adv0);
    float m1 = leaky(as_[n0 + 1] + adv1);

    float acc0 = __half2float(h2h[(unsigned)n0 * 64u + lane]);        // self, w=1
    float acc1 = __half2float(h2h[(unsigned)(n0 + 1) * 64u + lane]);
    float wsum0 = 0.f, wsum1 = 0.f;

    for (int j0 = beg; j0 < end; j0 += 64) {
        int rem = end - j0;
        int cnt = rem < 64 ? rem : 64;
        if (lane < cnt) {
            int j = j0 + lane;
            int s = col[j];
            bool is1 = (j >= mid);
            float adv = is1 ? adv1 : adv0;
            float m = is1 ? m1 : m0;
            float w = __expf(leaky(as_[s] + adv) - m);
            if (is1) wsum1 += w; else wsum0 += w;
            sw[wv][lane] = make_int2((int)((unsigned)s * 64u), __float_as_int(w));
        }
        int j = 0;
        for (; j + 8 <= cnt; j += 8) {
            int2 p[8];
#pragma unroll
            for (int q = 0; q < 8; ++q) p[q] = sw[wv][j + q];   // LDS broadcast
            __half hv[8];
#pragma unroll
            for (int q = 0; q < 8; ++q) hv[q] = h2h[(unsigned)p[q].x + lane];
#pragma unroll
            for (int q = 0; q < 8; ++q) {
                float w = __int_as_float(p[q].y);
                float v = __half2float(hv[q]);
                if (j0 + j + q < mid) acc0 = fmaf(w, v, acc0);   // uniform branch
                else                  acc1 = fmaf(w, v, acc1);
            }
        }
        for (; j < cnt; ++j) {
            int2 p = sw[wv][j];
            float w = __int_as_float(p.y);
            float v = __half2float(h2h[(unsigned)p.x + lane]);
            if (j0 + j < mid) acc0 = fmaf(w, v, acc0);
            else              acc1 = fmaf(w, v, acc1);
        }
    }
#pragma unroll
    for (int off = 32; off; off >>= 1) {
        wsum0 += __shfl_xor(wsum0, off);
        wsum1 += __shfl_xor(wsum1, off);
    }
    float bv = bias[lane];
    float o0 = acc0 / (wsum0 + 1.0f) + bv;
    float o1 = acc1 / (wsum1 + 1.0f) + bv;
    float e0 = (o0 > 0.f) ? o0 : expm1f(o0);
    float e1 = (o1 > 0.f) ? o1 : expm1f(o1);
    float h0 = h[(unsigned)n0 * 64u + lane] + e0;        // residual
    float h1 = h[(unsigned)(n0 + 1) * 64u + lane] + e1;

    if constexpr (!FUSE_OUT) {
        h[(unsigned)n0 * 64u + lane] = h0;
        h[(unsigned)(n0 + 1) * 64u + lane] = h1;
    } else {
        // out = h_row @ W_out + b_out, per node (wave-local LDS broadcast dot)
        sh[wv][lane] = h0;
        float o = (lane < 40) ? bs[lane] : 0.f;
#pragma unroll 8
        for (int k = 0; k < 64; ++k)
            o = fmaf(sh[wv][k], (lane < 40) ? Ws[k * 40 + lane] : 0.f, o);
        if (lane < 40) out[(unsigned)n0 * 40u + lane] = o;

        sh[wv][lane] = h1;
        float o2 = (lane < 40) ? bs[lane] : 0.f;
#pragma unroll 8
        for (int k = 0; k < 64; ++k)
            o2 = fmaf(sh[wv][k], (lane < 40) ? Ws[k * 40 + lane] : 0.f, o2);
        if (lane < 40) out[(unsigned)(n0 + 1) * 40u + lane] = o2;
    }
}

// ---------------- launcher ----------------

extern "C" void kernel_launch(void* const* d_in, const int* in_sizes, int n_in,
                              void* d_out, int out_size, void* d_ws, size_t ws_size,
                              hipStream_t stream) {
    const float* x        = (const float*)d_in[0];
    const int* ei         = (const int*)d_in[1];
    const float* W_in     = (const float*)d_in[2];
    const float* b_in     = (const float*)d_in[3];
    const float* W_conv   = (const float*)d_in[4];
    const float* att_src  = (const float*)d_in[5];
    const float* att_dst  = (const float*)d_in[6];
    const float* b_conv   = (const float*)d_in[7];
    const float* W_out    = (const float*)d_in[8];
    const float* b_out    = (const float*)d_in[9];
    float* out = (float*)d_out;

    char* w = (char*)d_ws;
    float*    hA    = (float*)w;    w += (size_t)N_NODES * 64 * 4;
    __half*   h2h   = (__half*)w;   w += (size_t)N_NODES * 64 * 2;
    float*    as_   = (float*)w;    w += (size_t)N_NODES * 4;
    float*    ad_   = (float*)w;    w += (size_t)N_NODES * 4;
    int*      rp    = (int*)w;      w += 400016;
    int*      scur2 = (int*)w;      w += NB2 * SCUR_PAD * 4;
    int*      bbase = (int*)w;      w += 4096;
    int*      col   = (int*)w;      w += (size_t)N_EDGES * 4;
    unsigned* pairs2= (unsigned*)w; w += (size_t)NB2 * CAP2 * 4;

    // CSR build (single-level 391-bucket partition)
    zero_counters_kernel<<<(NCOUNT + 255) / 256, 256, 0, stream>>>(scur2);
    partition_direct_kernel<<<PBLOCKS, 256, 0, stream>>>(ei, scur2, pairs2);
    scan_buckets_kernel<<<1, 512, 0, stream>>>(scur2, bbase);
    bucket_sort_kernel<<<NB2, 256, 0, stream>>>(scur2, bbase, pairs2, col, rp);

    // input transform (MFMA)
    gemm_in_mfma<<<(N_NODES + 63) / 64, 256, 0, stream>>>(x, W_in, b_in, hA, N_NODES);

    // N_NODES/2 pairs, 4 waves per block -> exact grid
    int agg_blocks = N_NODES / 8;   // 12500
    for (int l = 0; l < N_LAYERS; ++l) {
        gemm_fused_mfma<<<(N_NODES + 63) / 64, 256, 0, stream>>>(hA, W_conv + (size_t)l * 64 * 64,
                                                                 att_src + l * 64, att_dst + l * 64,
                                                                 as_, ad_, h2h, N_NODES);
        if (l < N_LAYERS - 1) {
            gat_aggregate_t<false><<<agg_blocks, 256, 0, stream>>>(rp, col, h2h, as_, ad_,
                                                                   b_conv + l * 64, hA,
                                                                   nullptr, nullptr, nullptr);
        } else {
            gat_aggregate_t<true><<<agg_blocks, 256, 0, stream>>>(rp, col, h2h, as_, ad_,
                                                                  b_conv + l * 64, hA,
                                                                  W_out, b_out, out);
        }
    }
}